// Round 1
// baseline (806.440 us; speedup 1.0000x reference)
//
#include <hip/hip_runtime.h>
#include <math.h>

#define HID 64
#define IN_DIM 128
#define POS_DIM 64
#define FT_IN 192
#define BN_EPS 1e-5f

static inline size_t align256(size_t x){ return (x + 255) & ~(size_t)255; }

__global__ void k_init(float* deg, int* cnt, float* stats, int n){
  int i = blockIdx.x*blockDim.x + threadIdx.x;
  if (i < n){ deg[i] = 0.f; cnt[i] = 0; }
  if (i < 128) stats[i] = 0.f;
}

__global__ void k_degcnt(const int* __restrict__ col, const float* __restrict__ ew,
                         float* deg, int* cnt, int E){
  int e = blockIdx.x*blockDim.x + threadIdx.x;
  if (e < E){
    int c = col[e];
    atomicAdd(&deg[c], ew[e]);
    atomicAdd(&cnt[c], 1);
  }
}

__global__ void k_dinv(const float* __restrict__ deg, float* dinv, int n){
  int i = blockIdx.x*blockDim.x + threadIdx.x;
  if (i < n) dinv[i] = rsqrtf(deg[i] + 1.0f);
}

// 3-phase exclusive scan of cnt[0..n) -> ptr[0..n], ptr[n] = total
__global__ void k_scanA(const int* __restrict__ cnt, int* ptr, int* bsum, int n){
  __shared__ int buf[256];
  int i = blockIdx.x*256 + threadIdx.x;
  int v = (i < n) ? cnt[i] : 0;
  buf[threadIdx.x] = v;
  __syncthreads();
  for (int off = 1; off < 256; off <<= 1){
    int t = (threadIdx.x >= off) ? buf[threadIdx.x - off] : 0;
    __syncthreads();
    buf[threadIdx.x] += t;
    __syncthreads();
  }
  if (i < n) ptr[i] = buf[threadIdx.x] - v;
  if (threadIdx.x == 255) bsum[blockIdx.x] = buf[255];
}

__global__ void k_scanB(int* bsum, int* ptr, int nblk, int n){
  __shared__ int buf[256];
  int v = (threadIdx.x < nblk) ? bsum[threadIdx.x] : 0;
  buf[threadIdx.x] = v;
  __syncthreads();
  for (int off = 1; off < 256; off <<= 1){
    int t = (threadIdx.x >= off) ? buf[threadIdx.x - off] : 0;
    __syncthreads();
    buf[threadIdx.x] += t;
    __syncthreads();
  }
  if (threadIdx.x < nblk) bsum[threadIdx.x] = buf[threadIdx.x] - v;
  if (threadIdx.x == 255) ptr[n] = buf[255];
}

__global__ void k_scanC(int* ptr, const int* __restrict__ bsum, int* fill, int n){
  int i = blockIdx.x*blockDim.x + threadIdx.x;
  if (i < n){
    int p = ptr[i] + bsum[i >> 8];
    ptr[i] = p;
    fill[i] = p;
  }
}

__global__ void k_fill(const int* __restrict__ row, const int* __restrict__ col,
                       const float* __restrict__ ew, const float* __restrict__ dinv,
                       int* fill, int* csr_src, float* csr_norm, int E){
  int e = blockIdx.x*blockDim.x + threadIdx.x;
  if (e < E){
    int c = col[e], r = row[e];
    int p = atomicAdd(&fill[c], 1);
    csr_src[p] = r;
    csr_norm[p] = dinv[r]*ew[e]*dinv[c];
  }
}

// h0 = concat(x, pe) @ ftW ; fused BN-stat accumulation (bias skipped: cancels in BN)
__global__ __launch_bounds__(256) void k_h0(
    const float* __restrict__ x, const int* __restrict__ positions,
    const float* __restrict__ ftW, float* __restrict__ h0, float* stats, int N)
{
  __shared__ float Ws[FT_IN*HID];     // 48KB
  __shared__ float pes[32][HID];      // 8KB
  __shared__ float red[512];          // 2KB
  int tx = threadIdx.x;
  int k = tx & 63;
  int g = tx >> 6;     // wave id; each wave owns 8 contiguous local nodes
  int n0 = blockIdx.x * 32;
  for (int t = tx; t < FT_IN*HID; t += 256) Ws[t] = ftW[t];
  float divt = expf((float)(k & ~1) * -0.14391157f);  // exp(2j * -ln(1e4)/64)
  for (int it = 0; it < 8; ++it){
    int ln = g*8 + it;
    int n = n0 + ln;
    float val = 0.f;
    if (n < N){
      float p = (float)positions[n];
      float ang = p * divt;
      val = (k & 1) ? cosf(ang) : sinf(ang);
    }
    pes[ln][k] = val;
  }
  __syncthreads();
  float ssum = 0.f, ssq = 0.f;
  for (int it = 0; it < 8; ++it){
    int ln = g*8 + it;
    int n = n0 + ln;
    if (n >= N) break;
    const float* xr = x + (size_t)n * IN_DIM;   // wave-uniform -> scalar loads
    float acc = 0.f;
    #pragma unroll 8
    for (int d = 0; d < IN_DIM; ++d) acc = fmaf(xr[d], Ws[d*HID + k], acc);
    #pragma unroll 8
    for (int d = 0; d < POS_DIM; ++d) acc = fmaf(pes[ln][d], Ws[(IN_DIM+d)*HID + k], acc);
    h0[(size_t)n*HID + k] = acc;
    ssum += acc; ssq += acc*acc;
  }
  red[tx] = ssum; red[256+tx] = ssq;
  __syncthreads();
  if (tx < 64){
    float s  = red[tx]     + red[64+tx]  + red[128+tx] + red[192+tx];
    float s2 = red[256+tx] + red[320+tx] + red[384+tx] + red[448+tx];
    atomicAdd(&stats[tx], s);
    atomicAdd(&stats[64+tx], s2);
  }
}

// hw = h @ W (64x64)
__global__ __launch_bounds__(256) void k_mm(
    const float* __restrict__ h, const float* __restrict__ W,
    float* __restrict__ hw, int N)
{
  __shared__ float Ws[HID*HID];   // 16KB
  __shared__ float hs[32*HID];    // 8KB
  int tx = threadIdx.x;
  int k = tx & 63, g = tx >> 6;
  int n0 = blockIdx.x * 32;
  for (int t = tx; t < HID*HID; t += 256) Ws[t] = W[t];
  for (int t = tx; t < 32*HID; t += 256){
    int n = n0 + (t >> 6);
    hs[t] = (n < N) ? h[(size_t)n0*HID + t] : 0.f;
  }
  __syncthreads();
  for (int it = 0; it < 8; ++it){
    int ln = g*8 + it;
    int n = n0 + ln;
    if (n >= N) break;
    float acc = 0.f;
    #pragma unroll 16
    for (int d = 0; d < HID; ++d) acc = fmaf(hs[ln*HID + d], Ws[d*HID + k], acc);
    hw[(size_t)n*HID + k] = acc;
  }
}

// agg[n][k] = dinv[n]^2 * hw[n][k] + sum_{e in CSR[n]} norm[e]*hw[src[e]][k]
// fused BN-stat accumulation; conv bias skipped (cancels in BN)
__global__ __launch_bounds__(256) void k_agg(
    const float* __restrict__ hw, const int* __restrict__ ptr,
    const int* __restrict__ csr_src, const float* __restrict__ csr_norm,
    const float* __restrict__ dinv, float* __restrict__ agg,
    float* stats, int N)
{
  __shared__ float red[512];
  int tx = threadIdx.x;
  int k = tx & 63, w = tx >> 6;
  int n0 = blockIdx.x * 16;
  float ssum = 0.f, ssq = 0.f;
  for (int it = 0; it < 4; ++it){
    int n = n0 + w*4 + it;
    if (n < N){
      float di = dinv[n];
      float acc = di*di*hw[(size_t)n*HID + k];
      int e0 = ptr[n], e1 = ptr[n+1];
      for (int e = e0; e < e1; ++e){
        int s = csr_src[e];              // wave-uniform -> scalar loads
        float nw = csr_norm[e];
        acc = fmaf(nw, hw[(size_t)s*HID + k], acc);
      }
      agg[(size_t)n*HID + k] = acc;
      ssum += acc; ssq += acc*acc;
    }
  }
  red[tx] = ssum; red[256+tx] = ssq;
  __syncthreads();
  if (tx < 64){
    float s  = red[tx]     + red[64+tx]  + red[128+tx] + red[192+tx];
    float s2 = red[256+tx] + red[320+tx] + red[384+tx] + red[448+tx];
    atomicAdd(&stats[tx], s);
    atomicAdd(&stats[64+tx], s2);
  }
}

// finalize BN coefficients, reset stats for next use
__global__ void k_fin(float* stats, const float* __restrict__ gamma,
                      const float* __restrict__ beta, float* coef, float invN){
  int k = threadIdx.x;  // 64 threads
  float s = stats[k], s2 = stats[64+k];
  float mean = s * invN;
  float var = s2 * invN - mean*mean;
  float rstd = rsqrtf(var + BN_EPS);
  float scale = rstd * gamma[k];
  coef[k] = scale;
  coef[64+k] = beta[k] - mean*scale;
  stats[k] = 0.f; stats[64+k] = 0.f;
}

// h = relu(src*scale + shift) (+ h if residual)
__global__ void k_apply(const float4* __restrict__ src, float* __restrict__ h,
                        const float* __restrict__ coef, int total4, int residual){
  int i = blockIdx.x*blockDim.x + threadIdx.x;
  if (i >= total4) return;
  float4 v = src[i];
  int k0 = (i*4) & 63;
  float4 r;
  r.x = fmaxf(fmaf(v.x, coef[k0+0], coef[64+k0+0]), 0.f);
  r.y = fmaxf(fmaf(v.y, coef[k0+1], coef[64+k0+1]), 0.f);
  r.z = fmaxf(fmaf(v.z, coef[k0+2], coef[64+k0+2]), 0.f);
  r.w = fmaxf(fmaf(v.w, coef[k0+3], coef[64+k0+3]), 0.f);
  float4* h4 = (float4*)h;
  if (residual){
    float4 o = h4[i];
    r.x += o.x; r.y += o.y; r.z += o.z; r.w += o.w;
  }
  h4[i] = r;
}

// out[n] = relu(h[n] @ W1 + b1) @ W2 + b2
__global__ __launch_bounds__(256) void k_out(
    const float* __restrict__ h, const float* __restrict__ W1,
    const float* __restrict__ b1, const float* __restrict__ W2,
    const float* __restrict__ b2, float* __restrict__ out, int N)
{
  int tx = threadIdx.x;
  int lane = tx & 63, w = tx >> 6;
  int n = blockIdx.x*4 + w;
  if (n >= N) return;
  float v = h[(size_t)n*HID + lane];
  int j = lane & 31;
  float t = b1[j];
  #pragma unroll 16
  for (int kk = 0; kk < HID; ++kk){
    t = fmaf(__shfl(v, kk, 64), W1[kk*32 + j], t);
  }
  float s = (lane < 32) ? fmaxf(t, 0.f) * W2[j] : 0.f;
  s += __shfl_down(s, 16, 64);
  s += __shfl_down(s, 8, 64);
  s += __shfl_down(s, 4, 64);
  s += __shfl_down(s, 2, 64);
  s += __shfl_down(s, 1, 64);
  if (lane == 0) out[n] = s + b2[0];
}

extern "C" void kernel_launch(void* const* d_in, const int* in_sizes, int n_in,
                              void* d_out, int out_size, void* d_ws, size_t ws_size,
                              hipStream_t stream)
{
  const float* x         = (const float*)d_in[0];
  const int*   ei        = (const int*)d_in[1];
  const float* ew        = (const float*)d_in[2];
  const int*   positions = (const int*)d_in[3];
  const float* ftW       = (const float*)d_in[4];
  // d_in[5] = ft_b : cancels in BN, unused
  const float* ft_gamma  = (const float*)d_in[6];
  const float* ft_beta   = (const float*)d_in[7];
  const float* convW     = (const float*)d_in[8];
  // d_in[9] = conv_b : cancels in BN, unused
  const float* bn_gamma  = (const float*)d_in[10];
  const float* bn_beta   = (const float*)d_in[11];
  const float* outW1     = (const float*)d_in[12];
  const float* outb1     = (const float*)d_in[13];
  const float* outW2     = (const float*)d_in[14];
  const float* outb2     = (const float*)d_in[15];
  float* out = (float*)d_out;

  int N = in_sizes[0] / IN_DIM;
  int E = in_sizes[1] / 2;
  const int* row  = ei;
  const int* colv = ei + E;

  // workspace carve (~46MB)
  char* p = (char*)d_ws;
  auto alloc = [&](size_t bytes){ char* r = p; p += align256(bytes); return r; };
  float* deg      = (float*)alloc((size_t)N*4);
  float* dinv     = (float*)alloc((size_t)N*4);
  int*   cnt      = (int*)  alloc((size_t)N*4);
  int*   ptr      = (int*)  alloc((size_t)(N+1)*4);
  int*   fill     = (int*)  alloc((size_t)N*4);
  int*   bsum     = (int*)  alloc((size_t)((N+255)/256)*4);
  int*   csr_src  = (int*)  alloc((size_t)E*4);
  float* csr_norm = (float*)alloc((size_t)E*4);
  float* hw       = (float*)alloc((size_t)N*HID*4);
  float* aggb     = (float*)alloc((size_t)N*HID*4);
  float* hbuf     = (float*)alloc((size_t)N*HID*4);
  float* stats    = (float*)alloc(128*4);
  float* coef     = (float*)alloc(128*4);

  int nb_n  = (N+255)/256;
  int nb_e  = (E+255)/256;
  int nblk  = (N+255)/256;
  int nb32  = (N+31)/32;
  int nb16  = (N+15)/16;
  int total4 = (N*HID)/4;
  int nb_a  = (total4+255)/256;
  float invN = 1.0f/(float)N;

  // CSR build (once; shared by all 3 layers)
  k_init  <<<nb_n,256,0,stream>>>(deg,cnt,stats,N);
  k_degcnt<<<nb_e,256,0,stream>>>(colv,ew,deg,cnt,E);
  k_dinv  <<<nb_n,256,0,stream>>>(deg,dinv,N);
  k_scanA <<<nblk,256,0,stream>>>(cnt,ptr,bsum,N);
  k_scanB <<<1,256,0,stream>>>(bsum,ptr,nblk,N);
  k_scanC <<<nb_n,256,0,stream>>>(ptr,bsum,fill,N);
  k_fill  <<<nb_e,256,0,stream>>>(row,colv,ew,dinv,fill,csr_src,csr_norm,E);

  // feature transform
  k_h0    <<<nb32,256,0,stream>>>(x,positions,ftW,aggb,stats,N);
  k_fin   <<<1,64,0,stream>>>(stats,ft_gamma,ft_beta,coef,invN);
  k_apply <<<nb_a,256,0,stream>>>((const float4*)aggb,hbuf,coef,total4,0);

  // GCN layers
  for (int i = 0; i < 3; ++i){
    k_mm    <<<nb32,256,0,stream>>>(hbuf, convW + (size_t)i*HID*HID, hw, N);
    k_agg   <<<nb16,256,0,stream>>>(hw,ptr,csr_src,csr_norm,dinv,aggb,stats,N);
    k_fin   <<<1,64,0,stream>>>(stats,bn_gamma+(size_t)i*HID,bn_beta+(size_t)i*HID,coef,invN);
    k_apply <<<nb_a,256,0,stream>>>((const float4*)aggb,hbuf,coef,total4,1);
  }

  // output MLP
  int nb4 = (N+3)/4;
  k_out<<<nb4,256,0,stream>>>(hbuf,outW1,outb1,outW2,outb2,out,N);
}

// Round 2
// 631.947 us; speedup vs baseline: 1.2761x; 1.2761x over previous
//
#include <hip/hip_runtime.h>
#include <math.h>

#define HID 64
#define IN_DIM 128
#define POS_DIM 64
#define FT_IN 192
#define BN_EPS 1e-5f
#define PAD 68   // LDS row stride (floats): 272B, 16B-aligned, conflict-light

static inline size_t align256(size_t x){ return (x + 255) & ~(size_t)255; }

// ---------------- CSR build (unchanged from round 0) ----------------

__global__ void k_init(float* deg, int* cnt, float* stats, int n){
  int i = blockIdx.x*blockDim.x + threadIdx.x;
  if (i < n){ deg[i] = 0.f; cnt[i] = 0; }
  if (i < 128) stats[i] = 0.f;
}

__global__ void k_degcnt(const int* __restrict__ col, const float* __restrict__ ew,
                         float* deg, int* cnt, int E){
  int e = blockIdx.x*blockDim.x + threadIdx.x;
  if (e < E){
    int c = col[e];
    atomicAdd(&deg[c], ew[e]);
    atomicAdd(&cnt[c], 1);
  }
}

__global__ void k_dinv(const float* __restrict__ deg, float* dinv, int n){
  int i = blockIdx.x*blockDim.x + threadIdx.x;
  if (i < n) dinv[i] = rsqrtf(deg[i] + 1.0f);
}

__global__ void k_scanA(const int* __restrict__ cnt, int* ptr, int* bsum, int n){
  __shared__ int buf[256];
  int i = blockIdx.x*256 + threadIdx.x;
  int v = (i < n) ? cnt[i] : 0;
  buf[threadIdx.x] = v;
  __syncthreads();
  for (int off = 1; off < 256; off <<= 1){
    int t = (threadIdx.x >= off) ? buf[threadIdx.x - off] : 0;
    __syncthreads();
    buf[threadIdx.x] += t;
    __syncthreads();
  }
  if (i < n) ptr[i] = buf[threadIdx.x] - v;
  if (threadIdx.x == 255) bsum[blockIdx.x] = buf[255];
}

__global__ void k_scanB(int* bsum, int* ptr, int nblk, int n){
  __shared__ int buf[256];
  int v = (threadIdx.x < nblk) ? bsum[threadIdx.x] : 0;
  buf[threadIdx.x] = v;
  __syncthreads();
  for (int off = 1; off < 256; off <<= 1){
    int t = (threadIdx.x >= off) ? buf[threadIdx.x - off] : 0;
    __syncthreads();
    buf[threadIdx.x] += t;
    __syncthreads();
  }
  if (threadIdx.x < nblk) bsum[threadIdx.x] = buf[threadIdx.x] - v;
  if (threadIdx.x == 255) ptr[n] = buf[255];
}

__global__ void k_scanC(int* ptr, const int* __restrict__ bsum, int* fill, int n){
  int i = blockIdx.x*blockDim.x + threadIdx.x;
  if (i < n){
    int p = ptr[i] + bsum[i >> 8];
    ptr[i] = p;
    fill[i] = p;
  }
}

__global__ void k_fill(const int* __restrict__ row, const int* __restrict__ col,
                       const float* __restrict__ ew, const float* __restrict__ dinv,
                       int* fill, int* csr_src, float* csr_norm, int E){
  int e = blockIdx.x*blockDim.x + threadIdx.x;
  if (e < E){
    int c = col[e], r = row[e];
    int p = atomicAdd(&fill[c], 1);
    csr_src[p] = r;
    csr_norm[p] = dinv[r]*ew[e]*dinv[c];
  }
}

// ---------------- register-tiled GEMM building block ----------------
// 64-node x 64-col tile, 256 threads, 4x4 micro-tile per thread.

#define MICRO_FMA(a, b, acc)                                   \
  acc[0].x = fmaf(a.x, b.x, acc[0].x);                         \
  acc[0].y = fmaf(a.x, b.y, acc[0].y);                         \
  acc[0].z = fmaf(a.x, b.z, acc[0].z);                         \
  acc[0].w = fmaf(a.x, b.w, acc[0].w);                         \
  acc[1].x = fmaf(a.y, b.x, acc[1].x);                         \
  acc[1].y = fmaf(a.y, b.y, acc[1].y);                         \
  acc[1].z = fmaf(a.y, b.z, acc[1].z);                         \
  acc[1].w = fmaf(a.y, b.w, acc[1].w);                         \
  acc[2].x = fmaf(a.z, b.x, acc[2].x);                         \
  acc[2].y = fmaf(a.z, b.y, acc[2].y);                         \
  acc[2].z = fmaf(a.z, b.z, acc[2].z);                         \
  acc[2].w = fmaf(a.z, b.w, acc[2].w);                         \
  acc[3].x = fmaf(a.w, b.x, acc[3].x);                         \
  acc[3].y = fmaf(a.w, b.y, acc[3].y);                         \
  acc[3].z = fmaf(a.w, b.z, acc[3].z);                         \
  acc[3].w = fmaf(a.w, b.w, acc[3].w);

// h0 = concat(x, pe) @ ftW ; bias skipped (cancels in BN); fused BN stats.
__global__ __launch_bounds__(256) void k_h0(
    const float* __restrict__ x, const int* __restrict__ positions,
    const float* __restrict__ ftW, float* __restrict__ h0, float* stats, int N)
{
  __shared__ __align__(16) float Xs[32*PAD];   // transposed [k][node]
  __shared__ __align__(16) float Wc[32*64];    // [k][col]
  __shared__ float redS[16*64];
  __shared__ float redQ[16*64];
  int tx = threadIdx.x;
  int n0 = blockIdx.x * 64;
  int c4 = (tx & 15) * 4;
  int r4 = (tx >> 4) * 4;
  float4 acc[4];
  acc[0] = acc[1] = acc[2] = acc[3] = make_float4(0.f,0.f,0.f,0.f);

  for (int kc = 0; kc < 6; ++kc){
    // stage W chunk [32][64]
    #pragma unroll
    for (int i = 0; i < 8; ++i)
      Wc[tx + i*256] = ftW[kc*2048 + tx + i*256];
    // stage operand chunk transposed
    if (kc < 4){
      #pragma unroll
      for (int i = 0; i < 2; ++i){
        int s = tx + i*256;              // 512 float4 slots
        int row = s >> 3, kk = (s & 7) * 4;
        float4 v = make_float4(0.f,0.f,0.f,0.f);
        int n = n0 + row;
        if (n < N) v = *(const float4*)&x[(size_t)n*IN_DIM + kc*32 + kk];
        Xs[(kk+0)*PAD + row] = v.x;
        Xs[(kk+1)*PAD + row] = v.y;
        Xs[(kk+2)*PAD + row] = v.z;
        Xs[(kk+3)*PAD + row] = v.w;
      }
    } else {
      #pragma unroll
      for (int i = 0; i < 4; ++i){
        int s = tx + i*256;              // 1024 (node,pair) slots
        int m = s & 63, jj = s >> 6;     // jj in 0..15
        int j = (kc-4)*16 + jj;          // global pair index
        int n = n0 + m;
        float sv = 0.f, cv = 0.f;
        if (n < N){
          float ang = (float)positions[n] * expf((float)(2*j) * -0.14391157f);
          sv = sinf(ang); cv = cosf(ang);
        }
        Xs[(2*jj+0)*PAD + m] = sv;
        Xs[(2*jj+1)*PAD + m] = cv;
      }
    }
    __syncthreads();
    #pragma unroll 8
    for (int k = 0; k < 32; ++k){
      float4 a = *(const float4*)(Xs + k*PAD + r4);
      float4 b = *(const float4*)(Wc + k*64 + c4);
      MICRO_FMA(a, b, acc);
    }
    __syncthreads();
  }

  // store + per-column stats
  float cs[4] = {0,0,0,0}, cq[4] = {0,0,0,0};
  #pragma unroll
  for (int i = 0; i < 4; ++i){
    int n = n0 + r4 + i;
    if (n < N) *(float4*)&h0[(size_t)n*HID + c4] = acc[i];
    float4 v = (n < N) ? acc[i] : make_float4(0,0,0,0);
    cs[0] += v.x; cs[1] += v.y; cs[2] += v.z; cs[3] += v.w;
    cq[0] += v.x*v.x; cq[1] += v.y*v.y; cq[2] += v.z*v.z; cq[3] += v.w*v.w;
  }
  int g = tx >> 4;
  #pragma unroll
  for (int j = 0; j < 4; ++j){
    redS[g*64 + c4 + j] = cs[j];
    redQ[g*64 + c4 + j] = cq[j];
  }
  __syncthreads();
  if (tx < 64){
    float s = 0.f, q = 0.f;
    #pragma unroll
    for (int gg = 0; gg < 16; ++gg){ s += redS[gg*64 + tx]; q += redQ[gg*64 + tx]; }
    atomicAdd(&stats[tx], s);
    atomicAdd(&stats[64+tx], q);
  }
}

// fused: h_new = relu(aggb*scale+shift) (+ hbuf if residual); hbuf = h_new;
//        hw = h_new @ W
__global__ __launch_bounds__(256) void k_layer(
    const float* __restrict__ aggb, const float* __restrict__ coef,
    float* __restrict__ hbuf, const float* __restrict__ W,
    float* __restrict__ hw, int N, int residual)
{
  __shared__ __align__(16) float Ws[64*64];
  __shared__ __align__(16) float Hs[64*PAD];
  int tx = threadIdx.x;
  int n0 = blockIdx.x * 64;
  #pragma unroll
  for (int i = 0; i < 16; ++i) Ws[tx + i*256] = W[tx + i*256];
  #pragma unroll
  for (int i = 0; i < 4; ++i){
    int s = tx + i*256;               // 1024 float4 slots
    int row = s >> 4, cc = (s & 15) * 4;
    int n = n0 + row;
    float4 r = make_float4(0.f,0.f,0.f,0.f);
    if (n < N){
      float4 v = *(const float4*)&aggb[(size_t)n*HID + cc];
      r.x = fmaxf(fmaf(v.x, coef[cc+0], coef[64+cc+0]), 0.f);
      r.y = fmaxf(fmaf(v.y, coef[cc+1], coef[64+cc+1]), 0.f);
      r.z = fmaxf(fmaf(v.z, coef[cc+2], coef[64+cc+2]), 0.f);
      r.w = fmaxf(fmaf(v.w, coef[cc+3], coef[64+cc+3]), 0.f);
      if (residual){
        float4 o = *(const float4*)&hbuf[(size_t)n*HID + cc];
        r.x += o.x; r.y += o.y; r.z += o.z; r.w += o.w;
      }
      *(float4*)&hbuf[(size_t)n*HID + cc] = r;
    }
    Hs[(cc+0)*PAD + row] = r.x;
    Hs[(cc+1)*PAD + row] = r.y;
    Hs[(cc+2)*PAD + row] = r.z;
    Hs[(cc+3)*PAD + row] = r.w;
  }
  __syncthreads();
  int c4 = (tx & 15) * 4;
  int r4 = (tx >> 4) * 4;
  float4 acc[4];
  acc[0] = acc[1] = acc[2] = acc[3] = make_float4(0.f,0.f,0.f,0.f);
  #pragma unroll 8
  for (int k = 0; k < 64; ++k){
    float4 a = *(const float4*)(Hs + k*PAD + r4);
    float4 b = *(const float4*)(Ws + k*64 + c4);
    MICRO_FMA(a, b, acc);
  }
  #pragma unroll
  for (int i = 0; i < 4; ++i){
    int n = n0 + r4 + i;
    if (n < N) *(float4*)&hw[(size_t)n*HID + c4] = acc[i];
  }
}

// agg[n][k] = dinv[n]^2 * hw[n][k] + sum_{e in CSR[n]} norm[e]*hw[src[e]][k]
// fused BN-stat accumulation
__global__ __launch_bounds__(256) void k_agg(
    const float* __restrict__ hw, const int* __restrict__ ptr,
    const int* __restrict__ csr_src, const float* __restrict__ csr_norm,
    const float* __restrict__ dinv, float* __restrict__ agg,
    float* stats, int N)
{
  __shared__ float red[512];
  int tx = threadIdx.x;
  int k = tx & 63, w = tx >> 6;
  int n0 = blockIdx.x * 16;
  float ssum = 0.f, ssq = 0.f;
  for (int it = 0; it < 4; ++it){
    int n = n0 + w*4 + it;
    if (n < N){
      float di = dinv[n];
      float acc = di*di*hw[(size_t)n*HID + k];
      int e0 = ptr[n], e1 = ptr[n+1];
      for (int e = e0; e < e1; ++e){
        int s = csr_src[e];
        float nw = csr_norm[e];
        acc = fmaf(nw, hw[(size_t)s*HID + k], acc);
      }
      agg[(size_t)n*HID + k] = acc;
      ssum += acc; ssq += acc*acc;
    }
  }
  red[tx] = ssum; red[256+tx] = ssq;
  __syncthreads();
  if (tx < 64){
    float s  = red[tx]     + red[64+tx]  + red[128+tx] + red[192+tx];
    float s2 = red[256+tx] + red[320+tx] + red[384+tx] + red[448+tx];
    atomicAdd(&stats[tx], s);
    atomicAdd(&stats[64+tx], s2);
  }
}

// finalize BN coefficients, reset stats for next use
__global__ void k_fin(float* stats, const float* __restrict__ gamma,
                      const float* __restrict__ beta, float* coef, float invN){
  int k = threadIdx.x;  // 64 threads
  float s = stats[k], s2 = stats[64+k];
  float mean = s * invN;
  float var = s2 * invN - mean*mean;
  float rstd = rsqrtf(var + BN_EPS);
  float scale = rstd * gamma[k];
  coef[k] = scale;
  coef[64+k] = beta[k] - mean*scale;
  stats[k] = 0.f; stats[64+k] = 0.f;
}

// fused final: h3 = relu(aggb*scale+shift)+hbuf ; out = relu(h3@W1+b1)@W2+b2
__global__ __launch_bounds__(256) void k_out(
    const float* __restrict__ aggb, const float* __restrict__ coef,
    const float* __restrict__ hbuf,
    const float* __restrict__ W1, const float* __restrict__ b1,
    const float* __restrict__ W2, const float* __restrict__ b2,
    float* __restrict__ out, int N)
{
  __shared__ __align__(16) float Hs[64*PAD];
  __shared__ float red[256];
  int tx = threadIdx.x;
  int n0 = blockIdx.x * 64;
  #pragma unroll
  for (int i = 0; i < 4; ++i){
    int s = tx + i*256;
    int row = s >> 4, cc = (s & 15) * 4;
    int n = n0 + row;
    float4 r = make_float4(0.f,0.f,0.f,0.f);
    if (n < N){
      float4 v = *(const float4*)&aggb[(size_t)n*HID + cc];
      r.x = fmaxf(fmaf(v.x, coef[cc+0], coef[64+cc+0]), 0.f);
      r.y = fmaxf(fmaf(v.y, coef[cc+1], coef[64+cc+1]), 0.f);
      r.z = fmaxf(fmaf(v.z, coef[cc+2], coef[64+cc+2]), 0.f);
      r.w = fmaxf(fmaf(v.w, coef[cc+3], coef[64+cc+3]), 0.f);
      float4 o = *(const float4*)&hbuf[(size_t)n*HID + cc];
      r.x += o.x; r.y += o.y; r.z += o.z; r.w += o.w;
    }
    Hs[(cc+0)*PAD + row] = r.x;
    Hs[(cc+1)*PAD + row] = r.y;
    Hs[(cc+2)*PAD + row] = r.z;
    Hs[(cc+3)*PAD + row] = r.w;
  }
  __syncthreads();
  int m = tx & 63, w = tx >> 6, j0 = w*8;
  float acc[8] = {0,0,0,0,0,0,0,0};
  #pragma unroll 8
  for (int k = 0; k < 64; ++k){
    float hv = Hs[k*PAD + m];
    #pragma unroll
    for (int j = 0; j < 8; ++j)
      acc[j] = fmaf(hv, W1[k*32 + j0 + j], acc[j]);
  }
  float part = 0.f;
  #pragma unroll
  for (int j = 0; j < 8; ++j)
    part += fmaxf(acc[j] + b1[j0+j], 0.f) * W2[j0+j];
  red[w*64 + m] = part;
  __syncthreads();
  if (tx < 64){
    int n = n0 + tx;
    if (n < N) out[n] = red[tx] + red[64+tx] + red[128+tx] + red[192+tx] + b2[0];
  }
}

extern "C" void kernel_launch(void* const* d_in, const int* in_sizes, int n_in,
                              void* d_out, int out_size, void* d_ws, size_t ws_size,
                              hipStream_t stream)
{
  const float* x         = (const float*)d_in[0];
  const int*   ei        = (const int*)d_in[1];
  const float* ew        = (const float*)d_in[2];
  const int*   positions = (const int*)d_in[3];
  const float* ftW       = (const float*)d_in[4];
  // d_in[5] = ft_b : cancels in BN, unused
  const float* ft_gamma  = (const float*)d_in[6];
  const float* ft_beta   = (const float*)d_in[7];
  const float* convW     = (const float*)d_in[8];
  // d_in[9] = conv_b : cancels in BN, unused
  const float* bn_gamma  = (const float*)d_in[10];
  const float* bn_beta   = (const float*)d_in[11];
  const float* outW1     = (const float*)d_in[12];
  const float* outb1     = (const float*)d_in[13];
  const float* outW2     = (const float*)d_in[14];
  const float* outb2     = (const float*)d_in[15];
  float* out = (float*)d_out;

  int N = in_sizes[0] / IN_DIM;
  int E = in_sizes[1] / 2;
  const int* row  = ei;
  const int* colv = ei + E;

  char* p = (char*)d_ws;
  auto alloc = [&](size_t bytes){ char* r = p; p += align256(bytes); return r; };
  float* deg      = (float*)alloc((size_t)N*4);
  float* dinv     = (float*)alloc((size_t)N*4);
  int*   cnt      = (int*)  alloc((size_t)N*4);
  int*   ptr      = (int*)  alloc((size_t)(N+1)*4);
  int*   fill     = (int*)  alloc((size_t)N*4);
  int*   bsum     = (int*)  alloc((size_t)((N+255)/256)*4);
  int*   csr_src  = (int*)  alloc((size_t)E*4);
  float* csr_norm = (float*)alloc((size_t)E*4);
  float* hw       = (float*)alloc((size_t)N*HID*4);
  float* aggb     = (float*)alloc((size_t)N*HID*4);
  float* hbuf     = (float*)alloc((size_t)N*HID*4);
  float* stats    = (float*)alloc(128*4);
  float* coef     = (float*)alloc(128*4);

  int nb_n  = (N+255)/256;
  int nb_e  = (E+255)/256;
  int nblk  = (N+255)/256;
  int nb64  = (N+63)/64;
  int nb16  = (N+15)/16;
  float invN = 1.0f/(float)N;

  // CSR build (once; shared by all 3 layers)
  k_init  <<<nb_n,256,0,stream>>>(deg,cnt,stats,N);
  k_degcnt<<<nb_e,256,0,stream>>>(colv,ew,deg,cnt,E);
  k_dinv  <<<nb_n,256,0,stream>>>(deg,dinv,N);
  k_scanA <<<nblk,256,0,stream>>>(cnt,ptr,bsum,N);
  k_scanB <<<1,256,0,stream>>>(bsum,ptr,nblk,N);
  k_scanC <<<nb_n,256,0,stream>>>(ptr,bsum,fill,N);
  k_fill  <<<nb_e,256,0,stream>>>(row,colv,ew,dinv,fill,csr_src,csr_norm,E);

  // feature transform (pre-BN values -> aggb, stats fused)
  k_h0  <<<nb64,256,0,stream>>>(x,positions,ftW,aggb,stats,N);
  k_fin <<<1,64,0,stream>>>(stats,ft_gamma,ft_beta,coef,invN);

  // GCN layers: k_layer applies previous BN (+residual), stores h, computes h@W
  for (int i = 0; i < 3; ++i){
    k_layer<<<nb64,256,0,stream>>>(aggb,coef,hbuf,convW + (size_t)i*HID*HID,hw,N,(i>0)?1:0);
    k_agg  <<<nb16,256,0,stream>>>(hw,ptr,csr_src,csr_norm,dinv,aggb,stats,N);
    k_fin  <<<1,64,0,stream>>>(stats,bn_gamma+(size_t)i*HID,bn_beta+(size_t)i*HID,coef,invN);
  }

  // final apply + output MLP
  k_out<<<nb64,256,0,stream>>>(aggb,coef,hbuf,outW1,outb1,outW2,outb2,out,N);
}

// Round 3
// 530.947 us; speedup vs baseline: 1.5189x; 1.1902x over previous
//
#include <hip/hip_runtime.h>
#include <hip/hip_fp16.h>
#include <math.h>

#define HID 64
#define IN_DIM 128
#define POS_DIM 64
#define FT_IN 192
#define BN_EPS 1e-5f
#define PAD 68   // LDS row stride (floats): 272B, 16B-aligned, conflict-light

static inline size_t align256(size_t x){ return (x + 255) & ~(size_t)255; }

// ---------------- CSR build ----------------

__global__ void k_init(float* deg, int* cnt, float* stats, int n){
  int i = blockIdx.x*blockDim.x + threadIdx.x;
  if (i < n){ deg[i] = 0.f; cnt[i] = 0; }
  if (i < 128) stats[i] = 0.f;
}

__global__ void k_degcnt(const int* __restrict__ col, const float* __restrict__ ew,
                         float* deg, int* cnt, int E){
  int e = blockIdx.x*blockDim.x + threadIdx.x;
  if (e < E){
    int c = col[e];
    atomicAdd(&deg[c], ew[e]);
    atomicAdd(&cnt[c], 1);
  }
}

__global__ void k_dinv(const float* __restrict__ deg, float* dinv, int n){
  int i = blockIdx.x*blockDim.x + threadIdx.x;
  if (i < n) dinv[i] = rsqrtf(deg[i] + 1.0f);
}

__global__ void k_scanA(const int* __restrict__ cnt, int* ptr, int* bsum, int n){
  __shared__ int buf[256];
  int i = blockIdx.x*256 + threadIdx.x;
  int v = (i < n) ? cnt[i] : 0;
  buf[threadIdx.x] = v;
  __syncthreads();
  for (int off = 1; off < 256; off <<= 1){
    int t = (threadIdx.x >= off) ? buf[threadIdx.x - off] : 0;
    __syncthreads();
    buf[threadIdx.x] += t;
    __syncthreads();
  }
  if (i < n) ptr[i] = buf[threadIdx.x] - v;
  if (threadIdx.x == 255) bsum[blockIdx.x] = buf[255];
}

__global__ void k_scanB(int* bsum, int* ptr, int nblk, int n){
  __shared__ int buf[256];
  int v = (threadIdx.x < nblk) ? bsum[threadIdx.x] : 0;
  buf[threadIdx.x] = v;
  __syncthreads();
  for (int off = 1; off < 256; off <<= 1){
    int t = (threadIdx.x >= off) ? buf[threadIdx.x - off] : 0;
    __syncthreads();
    buf[threadIdx.x] += t;
    __syncthreads();
  }
  if (threadIdx.x < nblk) bsum[threadIdx.x] = buf[threadIdx.x] - v;
  if (threadIdx.x == 255) ptr[n] = buf[255];
}

__global__ void k_scanC(int* ptr, const int* __restrict__ bsum, int* fill, int n){
  int i = blockIdx.x*blockDim.x + threadIdx.x;
  if (i < n){
    int p = ptr[i] + bsum[i >> 8];
    ptr[i] = p;
    fill[i] = p;
  }
}

__global__ void k_fill(const int* __restrict__ row, const int* __restrict__ col,
                       const float* __restrict__ ew, const float* __restrict__ dinv,
                       int* fill, int* csr_src, float* csr_norm, int E){
  int e = blockIdx.x*blockDim.x + threadIdx.x;
  if (e < E){
    int c = col[e], r = row[e];
    int p = atomicAdd(&fill[c], 1);
    csr_src[p] = r;
    csr_norm[p] = dinv[r]*ew[e]*dinv[c];
  }
}

// ---------------- register-tiled GEMM building block ----------------

#define MICRO_FMA(a, b, acc)                                   \
  acc[0].x = fmaf(a.x, b.x, acc[0].x);                         \
  acc[0].y = fmaf(a.x, b.y, acc[0].y);                         \
  acc[0].z = fmaf(a.x, b.z, acc[0].z);                         \
  acc[0].w = fmaf(a.x, b.w, acc[0].w);                         \
  acc[1].x = fmaf(a.y, b.x, acc[1].x);                         \
  acc[1].y = fmaf(a.y, b.y, acc[1].y);                         \
  acc[1].z = fmaf(a.y, b.z, acc[1].z);                         \
  acc[1].w = fmaf(a.y, b.w, acc[1].w);                         \
  acc[2].x = fmaf(a.z, b.x, acc[2].x);                         \
  acc[2].y = fmaf(a.z, b.y, acc[2].y);                         \
  acc[2].z = fmaf(a.z, b.z, acc[2].z);                         \
  acc[2].w = fmaf(a.z, b.w, acc[2].w);                         \
  acc[3].x = fmaf(a.w, b.x, acc[3].x);                         \
  acc[3].y = fmaf(a.w, b.y, acc[3].y);                         \
  acc[3].z = fmaf(a.w, b.z, acc[3].z);                         \
  acc[3].w = fmaf(a.w, b.w, acc[3].w);

// h0 = concat(x, pe) @ ftW ; bias skipped (cancels in BN); fused BN stats.
__global__ __launch_bounds__(256) void k_h0(
    const float* __restrict__ x, const int* __restrict__ positions,
    const float* __restrict__ ftW, float* __restrict__ h0, float* stats, int N)
{
  __shared__ __align__(16) float Xs[32*PAD];   // transposed [k][node]
  __shared__ __align__(16) float Wc[32*64];    // [k][col]
  __shared__ float redS[16*64];
  __shared__ float redQ[16*64];
  int tx = threadIdx.x;
  int n0 = blockIdx.x * 64;
  int c4 = (tx & 15) * 4;
  int r4 = (tx >> 4) * 4;
  float4 acc[4];
  acc[0] = acc[1] = acc[2] = acc[3] = make_float4(0.f,0.f,0.f,0.f);

  for (int kc = 0; kc < 6; ++kc){
    #pragma unroll
    for (int i = 0; i < 8; ++i)
      Wc[tx + i*256] = ftW[kc*2048 + tx + i*256];
    if (kc < 4){
      #pragma unroll
      for (int i = 0; i < 2; ++i){
        int s = tx + i*256;
        int row = s >> 3, kk = (s & 7) * 4;
        float4 v = make_float4(0.f,0.f,0.f,0.f);
        int n = n0 + row;
        if (n < N) v = *(const float4*)&x[(size_t)n*IN_DIM + kc*32 + kk];
        Xs[(kk+0)*PAD + row] = v.x;
        Xs[(kk+1)*PAD + row] = v.y;
        Xs[(kk+2)*PAD + row] = v.z;
        Xs[(kk+3)*PAD + row] = v.w;
      }
    } else {
      #pragma unroll
      for (int i = 0; i < 4; ++i){
        int s = tx + i*256;
        int m = s & 63, jj = s >> 6;
        int j = (kc-4)*16 + jj;
        int n = n0 + m;
        float sv = 0.f, cv = 0.f;
        if (n < N){
          float ang = (float)positions[n] * expf((float)(2*j) * -0.14391157f);
          sv = sinf(ang); cv = cosf(ang);
        }
        Xs[(2*jj+0)*PAD + m] = sv;
        Xs[(2*jj+1)*PAD + m] = cv;
      }
    }
    __syncthreads();
    #pragma unroll 8
    for (int k = 0; k < 32; ++k){
      float4 a = *(const float4*)(Xs + k*PAD + r4);
      float4 b = *(const float4*)(Wc + k*64 + c4);
      MICRO_FMA(a, b, acc);
    }
    __syncthreads();
  }

  float cs[4] = {0,0,0,0}, cq[4] = {0,0,0,0};
  #pragma unroll
  for (int i = 0; i < 4; ++i){
    int n = n0 + r4 + i;
    if (n < N) *(float4*)&h0[(size_t)n*HID + c4] = acc[i];
    float4 v = (n < N) ? acc[i] : make_float4(0,0,0,0);
    cs[0] += v.x; cs[1] += v.y; cs[2] += v.z; cs[3] += v.w;
    cq[0] += v.x*v.x; cq[1] += v.y*v.y; cq[2] += v.z*v.z; cq[3] += v.w*v.w;
  }
  int g = tx >> 4;
  #pragma unroll
  for (int j = 0; j < 4; ++j){
    redS[g*64 + c4 + j] = cs[j];
    redQ[g*64 + c4 + j] = cq[j];
  }
  __syncthreads();
  if (tx < 64){
    float s = 0.f, q = 0.f;
    #pragma unroll
    for (int gg = 0; gg < 16; ++gg){ s += redS[gg*64 + tx]; q += redQ[gg*64 + tx]; }
    atomicAdd(&stats[tx], s);
    atomicAdd(&stats[64+tx], q);
  }
}

// fused: h_new = relu(aggb*scale+shift) (+ hbuf if residual); hbuf = h_new;
//        hw = h_new @ W  (stored fp16 for the gather kernel)
__global__ __launch_bounds__(256) void k_layer(
    const float* __restrict__ aggb, const float* __restrict__ coef,
    float* __restrict__ hbuf, const float* __restrict__ W,
    __half* __restrict__ hwh, int N, int residual)
{
  __shared__ __align__(16) float Ws[64*64];
  __shared__ __align__(16) float Hs[64*PAD];
  int tx = threadIdx.x;
  int n0 = blockIdx.x * 64;
  #pragma unroll
  for (int i = 0; i < 16; ++i) Ws[tx + i*256] = W[tx + i*256];
  #pragma unroll
  for (int i = 0; i < 4; ++i){
    int s = tx + i*256;
    int row = s >> 4, cc = (s & 15) * 4;
    int n = n0 + row;
    float4 r = make_float4(0.f,0.f,0.f,0.f);
    if (n < N){
      float4 v = *(const float4*)&aggb[(size_t)n*HID + cc];
      r.x = fmaxf(fmaf(v.x, coef[cc+0], coef[64+cc+0]), 0.f);
      r.y = fmaxf(fmaf(v.y, coef[cc+1], coef[64+cc+1]), 0.f);
      r.z = fmaxf(fmaf(v.z, coef[cc+2], coef[64+cc+2]), 0.f);
      r.w = fmaxf(fmaf(v.w, coef[cc+3], coef[64+cc+3]), 0.f);
      if (residual){
        float4 o = *(const float4*)&hbuf[(size_t)n*HID + cc];
        r.x += o.x; r.y += o.y; r.z += o.z; r.w += o.w;
      }
      *(float4*)&hbuf[(size_t)n*HID + cc] = r;
    }
    Hs[(cc+0)*PAD + row] = r.x;
    Hs[(cc+1)*PAD + row] = r.y;
    Hs[(cc+2)*PAD + row] = r.z;
    Hs[(cc+3)*PAD + row] = r.w;
  }
  __syncthreads();
  int c4 = (tx & 15) * 4;
  int r4 = (tx >> 4) * 4;
  float4 acc[4];
  acc[0] = acc[1] = acc[2] = acc[3] = make_float4(0.f,0.f,0.f,0.f);
  #pragma unroll 8
  for (int k = 0; k < 64; ++k){
    float4 a = *(const float4*)(Hs + k*PAD + r4);
    float4 b = *(const float4*)(Ws + k*64 + c4);
    MICRO_FMA(a, b, acc);
  }
  #pragma unroll
  for (int i = 0; i < 4; ++i){
    int n = n0 + r4 + i;
    if (n < N){
      __half2 h01 = __floats2half2_rn(acc[i].x, acc[i].y);
      __half2 h23 = __floats2half2_rn(acc[i].z, acc[i].w);
      *(__half2*)&hwh[(size_t)n*HID + c4]     = h01;
      *(__half2*)&hwh[(size_t)n*HID + c4 + 2] = h23;
    }
  }
}

// agg[n][k] = dinv[n]^2 * hw[n][k] + sum_{e} norm[e]*hw[src[e]][k]  (hw fp16)
// batched edge prefetch + 4-way independent accumulator chains (MLP)
__global__ __launch_bounds__(256) void k_agg(
    const __half* __restrict__ hwh, const int* __restrict__ ptr,
    const int* __restrict__ csr_src, const float* __restrict__ csr_norm,
    const float* __restrict__ dinv, float* __restrict__ agg,
    float* stats, int N)
{
  __shared__ float red[512];
  int tx = threadIdx.x;
  int k = tx & 63, w = tx >> 6;
  int n0 = blockIdx.x * 16;
  float ssum = 0.f, ssq = 0.f;
  for (int it = 0; it < 4; ++it){
    int n = n0 + w*4 + it;
    if (n < N){
      float di = dinv[n];
      float acc0 = di*di*__half2float(hwh[(size_t)n*HID + k]);
      float acc1 = 0.f, acc2 = 0.f, acc3 = 0.f;
      int e0 = ptr[n], e1 = ptr[n+1];
      for (int eb = e0; eb < e1; eb += 64){
        int m = e1 - eb; if (m > 64) m = 64;
        int   se = (k < m) ? csr_src[eb + k] : 0;
        float ne = (k < m) ? csr_norm[eb + k] : 0.f;
        int j = 0;
        for (; j + 4 <= m; j += 4){
          int   s0 = __shfl(se, j,   64);
          int   s1 = __shfl(se, j+1, 64);
          int   s2 = __shfl(se, j+2, 64);
          int   s3 = __shfl(se, j+3, 64);
          float w0 = __shfl(ne, j,   64);
          float w1 = __shfl(ne, j+1, 64);
          float w2 = __shfl(ne, j+2, 64);
          float w3 = __shfl(ne, j+3, 64);
          float g0 = __half2float(hwh[(size_t)s0*HID + k]);
          float g1 = __half2float(hwh[(size_t)s1*HID + k]);
          float g2 = __half2float(hwh[(size_t)s2*HID + k]);
          float g3 = __half2float(hwh[(size_t)s3*HID + k]);
          acc0 = fmaf(w0, g0, acc0);
          acc1 = fmaf(w1, g1, acc1);
          acc2 = fmaf(w2, g2, acc2);
          acc3 = fmaf(w3, g3, acc3);
        }
        for (; j < m; ++j){
          int   s0 = __shfl(se, j, 64);
          float w0 = __shfl(ne, j, 64);
          acc0 = fmaf(w0, __half2float(hwh[(size_t)s0*HID + k]), acc0);
        }
      }
      float acc = (acc0 + acc1) + (acc2 + acc3);
      agg[(size_t)n*HID + k] = acc;
      ssum += acc; ssq += acc*acc;
    }
  }
  red[tx] = ssum; red[256+tx] = ssq;
  __syncthreads();
  if (tx < 64){
    float s  = red[tx]     + red[64+tx]  + red[128+tx] + red[192+tx];
    float s2 = red[256+tx] + red[320+tx] + red[384+tx] + red[448+tx];
    atomicAdd(&stats[tx], s);
    atomicAdd(&stats[64+tx], s2);
  }
}

// finalize BN coefficients, reset stats for next use
__global__ void k_fin(float* stats, const float* __restrict__ gamma,
                      const float* __restrict__ beta, float* coef, float invN){
  int k = threadIdx.x;  // 64 threads
  float s = stats[k], s2 = stats[64+k];
  float mean = s * invN;
  float var = s2 * invN - mean*mean;
  float rstd = rsqrtf(var + BN_EPS);
  float scale = rstd * gamma[k];
  coef[k] = scale;
  coef[64+k] = beta[k] - mean*scale;
  stats[k] = 0.f; stats[64+k] = 0.f;
}

// fused final: h3 = relu(aggb*scale+shift)+hbuf ; out = relu(h3@W1+b1)@W2+b2
__global__ __launch_bounds__(256) void k_out(
    const float* __restrict__ aggb, const float* __restrict__ coef,
    const float* __restrict__ hbuf,
    const float* __restrict__ W1, const float* __restrict__ b1,
    const float* __restrict__ W2, const float* __restrict__ b2,
    float* __restrict__ out, int N)
{
  __shared__ __align__(16) float Hs[64*PAD];
  __shared__ float red[256];
  int tx = threadIdx.x;
  int n0 = blockIdx.x * 64;
  #pragma unroll
  for (int i = 0; i < 4; ++i){
    int s = tx + i*256;
    int row = s >> 4, cc = (s & 15) * 4;
    int n = n0 + row;
    float4 r = make_float4(0.f,0.f,0.f,0.f);
    if (n < N){
      float4 v = *(const float4*)&aggb[(size_t)n*HID + cc];
      r.x = fmaxf(fmaf(v.x, coef[cc+0], coef[64+cc+0]), 0.f);
      r.y = fmaxf(fmaf(v.y, coef[cc+1], coef[64+cc+1]), 0.f);
      r.z = fmaxf(fmaf(v.z, coef[cc+2], coef[64+cc+2]), 0.f);
      r.w = fmaxf(fmaf(v.w, coef[cc+3], coef[64+cc+3]), 0.f);
      float4 o = *(const float4*)&hbuf[(size_t)n*HID + cc];
      r.x += o.x; r.y += o.y; r.z += o.z; r.w += o.w;
    }
    Hs[(cc+0)*PAD + row] = r.x;
    Hs[(cc+1)*PAD + row] = r.y;
    Hs[(cc+2)*PAD + row] = r.z;
    Hs[(cc+3)*PAD + row] = r.w;
  }
  __syncthreads();
  int m = tx & 63, w = tx >> 6, j0 = w*8;
  float acc[8] = {0,0,0,0,0,0,0,0};
  #pragma unroll 8
  for (int k = 0; k < 64; ++k){
    float hv = Hs[k*PAD + m];
    #pragma unroll
    for (int j = 0; j < 8; ++j)
      acc[j] = fmaf(hv, W1[k*32 + j0 + j], acc[j]);
  }
  float part = 0.f;
  #pragma unroll
  for (int j = 0; j < 8; ++j)
    part += fmaxf(acc[j] + b1[j0+j], 0.f) * W2[j0+j];
  red[w*64 + m] = part;
  __syncthreads();
  if (tx < 64){
    int n = n0 + tx;
    if (n < N) out[n] = red[tx] + red[64+tx] + red[128+tx] + red[192+tx] + b2[0];
  }
}

extern "C" void kernel_launch(void* const* d_in, const int* in_sizes, int n_in,
                              void* d_out, int out_size, void* d_ws, size_t ws_size,
                              hipStream_t stream)
{
  const float* x         = (const float*)d_in[0];
  const int*   ei        = (const int*)d_in[1];
  const float* ew        = (const float*)d_in[2];
  const int*   positions = (const int*)d_in[3];
  const float* ftW       = (const float*)d_in[4];
  const float* ft_gamma  = (const float*)d_in[6];
  const float* ft_beta   = (const float*)d_in[7];
  const float* convW     = (const float*)d_in[8];
  const float* bn_gamma  = (const float*)d_in[10];
  const float* bn_beta   = (const float*)d_in[11];
  const float* outW1     = (const float*)d_in[12];
  const float* outb1     = (const float*)d_in[13];
  const float* outW2     = (const float*)d_in[14];
  const float* outb2     = (const float*)d_in[15];
  float* out = (float*)d_out;

  int N = in_sizes[0] / IN_DIM;
  int E = in_sizes[1] / 2;
  const int* row  = ei;
  const int* colv = ei + E;

  char* p = (char*)d_ws;
  auto alloc = [&](size_t bytes){ char* r = p; p += align256(bytes); return r; };
  float* deg      = (float*)alloc((size_t)N*4);
  float* dinv     = (float*)alloc((size_t)N*4);
  int*   cnt      = (int*)  alloc((size_t)N*4);
  int*   ptr      = (int*)  alloc((size_t)(N+1)*4);
  int*   fill     = (int*)  alloc((size_t)N*4);
  int*   bsum     = (int*)  alloc((size_t)((N+255)/256)*4);
  int*   csr_src  = (int*)  alloc((size_t)E*4);
  float* csr_norm = (float*)alloc((size_t)E*4);
  __half* hwh     = (__half*)alloc((size_t)N*HID*2);
  float* aggb     = (float*)alloc((size_t)N*HID*4);
  float* hbuf     = (float*)alloc((size_t)N*HID*4);
  float* stats    = (float*)alloc(128*4);
  float* coef     = (float*)alloc(128*4);

  int nb_n  = (N+255)/256;
  int nb_e  = (E+255)/256;
  int nblk  = (N+255)/256;
  int nb64  = (N+63)/64;
  int nb16  = (N+15)/16;
  float invN = 1.0f/(float)N;

  // CSR build (once; shared by all 3 layers)
  k_init  <<<nb_n,256,0,stream>>>(deg,cnt,stats,N);
  k_degcnt<<<nb_e,256,0,stream>>>(colv,ew,deg,cnt,E);
  k_dinv  <<<nb_n,256,0,stream>>>(deg,dinv,N);
  k_scanA <<<nblk,256,0,stream>>>(cnt,ptr,bsum,N);
  k_scanB <<<1,256,0,stream>>>(bsum,ptr,nblk,N);
  k_scanC <<<nb_n,256,0,stream>>>(ptr,bsum,fill,N);
  k_fill  <<<nb_e,256,0,stream>>>(row,colv,ew,dinv,fill,csr_src,csr_norm,E);

  // feature transform (pre-BN values -> aggb, stats fused)
  k_h0  <<<nb64,256,0,stream>>>(x,positions,ftW,aggb,stats,N);
  k_fin <<<1,64,0,stream>>>(stats,ft_gamma,ft_beta,coef,invN);

  // GCN layers
  for (int i = 0; i < 3; ++i){
    k_layer<<<nb64,256,0,stream>>>(aggb,coef,hbuf,convW + (size_t)i*HID*HID,hwh,N,(i>0)?1:0);
    k_agg  <<<nb16,256,0,stream>>>(hwh,ptr,csr_src,csr_norm,dinv,aggb,stats,N);
    k_fin  <<<1,64,0,stream>>>(stats,bn_gamma+(size_t)i*HID,bn_beta+(size_t)i*HID,coef,invN);
  }

  // final apply + output MLP
  k_out<<<nb64,256,0,stream>>>(aggb,coef,hbuf,outW1,outb1,outW2,outb2,out,N);
}